// Round 4
// baseline (719.661 us; speedup 1.0000x reference)
//
#include <hip/hip_runtime.h>
#include <math.h>

// TopKRouter: logits = x @ gate_w^T  (16384x4096 @ 4096x64), mask -> -inf,
// softmax, top-2, renormalized top-2 probs. Outputs concatenated fp32:
//   logits [16384*64] | probs [16384*64] | top_k_probs [16384*2] | top_k_indices [16384*2]
// (indices written as float values; harness reads the whole buffer as fp32)

#define TOKENS  16384
#define HIDDEN  4096
#define NEXP    64

__global__ __launch_bounds__(512, 2)
void topk_router_kernel(const float* __restrict__ x,
                        const int* __restrict__ mask,     // bool arrives as int32/elem
                        const float* __restrict__ gw,
                        float* __restrict__ out)
{
    // lane = token within block (64 tokens/block), wave = expert group (8 experts/wave)
    __shared__ float slog[64][65];      // [token][expert], +1 pad -> conflict-free
    __shared__ float smax[64];
    __shared__ float sinv[64];
    __shared__ unsigned char smask[64];

    const int tid   = threadIdx.x;
    const int lane  = tid & 63;
    const int wave  = tid >> 6;                                  // 0..7
    const int tok0  = blockIdx.x * 64;
    const int token = tok0 + lane;
    const int e0    = __builtin_amdgcn_readfirstlane(wave << 3); // wave-uniform expert base

    if (tid < NEXP) smask[tid] = (mask[tid] != 0) ? 1 : 0;

    const float* __restrict__ xrow = x + (size_t)token * HIDDEN;

    float acc[8] = {0.f,0.f,0.f,0.f,0.f,0.f,0.f,0.f};

    // software-pipelined x chunks of 16 floats; gate_w loads are wave-uniform
    float4 xv[4], xn[4];
    #pragma unroll
    for (int i = 0; i < 4; ++i)
        xv[i] = *reinterpret_cast<const float4*>(xrow + 4*i);

    for (int k = 0; k < HIDDEN; k += 16) {
        if (k + 16 < HIDDEN) {
            #pragma unroll
            for (int i = 0; i < 4; ++i)
                xn[i] = *reinterpret_cast<const float4*>(xrow + k + 16 + 4*i);
        }
        #pragma unroll
        for (int j = 0; j < 8; ++j) {
            const float* wrow = gw + (size_t)(e0 + j) * HIDDEN + k;
            #pragma unroll
            for (int i = 0; i < 4; ++i) {
                float4 wv = *reinterpret_cast<const float4*>(wrow + 4*i);
                acc[j] = fmaf(xv[i].x, wv.x, acc[j]);
                acc[j] = fmaf(xv[i].y, wv.y, acc[j]);
                acc[j] = fmaf(xv[i].z, wv.z, acc[j]);
                acc[j] = fmaf(xv[i].w, wv.w, acc[j]);
            }
        }
        #pragma unroll
        for (int i = 0; i < 4; ++i) xv[i] = xn[i];
    }

    #pragma unroll
    for (int j = 0; j < 8; ++j)
        slog[lane][e0 + j] = acc[j];

    __syncthreads();

    // per-token stats + top-2: one thread per token (wave 0 only; cheap vs GEMM)
    if (tid < 64) {
        float m = -INFINITY, b2 = -INFINITY;
        int i1 = 0, i2 = 0;
        for (int e = 0; e < NEXP; ++e) {
            float lv = smask[e] ? slog[tid][e] : -INFINITY;
            if (lv > m)       { b2 = m;  i2 = i1; m = lv; i1 = e; }
            else if (lv > b2) { b2 = lv; i2 = e; }
        }
        float s = 0.f;
        for (int e = 0; e < NEXP; ++e) {
            float lv = smask[e] ? slog[tid][e] : -INFINITY;
            s += expf(lv - m);
        }
        smax[tid] = m;
        sinv[tid] = 1.0f / s;

        // renormalized top-2: e1 = exp(m-m) = 1
        float e2 = expf(b2 - m);
        float r  = 1.0f / (1.0f + e2);
        const int t = tok0 + tid;
        float* tkp = out + (size_t)2 * TOKENS * NEXP;
        float* tki = tkp + (size_t)2 * TOKENS;
        tkp[2*t]     = r;
        tkp[2*t + 1] = e2 * r;
        tki[2*t]     = (float)i1;
        tki[2*t + 1] = (float)i2;
    }

    __syncthreads();

    // coalesced logits + probs writes: 4096 elems/block, 8 per thread
    float* logits_out = out;
    float* probs_out  = out + (size_t)TOKENS * NEXP;
    const int base = tok0 * NEXP;
    #pragma unroll
    for (int i = 0; i < 8; ++i) {
        int idx = i * 512 + tid;
        int tok = idx >> 6;
        int e   = idx & 63;
        float lv = smask[e] ? slog[tok][e] : -INFINITY;
        logits_out[base + idx] = lv;
        probs_out[base + idx]  = expf(lv - smax[tok]) * sinv[tok];
    }
}

extern "C" void kernel_launch(void* const* d_in, const int* in_sizes, int n_in,
                              void* d_out, int out_size, void* d_ws, size_t ws_size,
                              hipStream_t stream) {
    const float* x    = (const float*)d_in[0];
    const int*   mask = (const int*)d_in[1];   // jnp bool -> int32 on the wire
    const float* gw   = (const float*)d_in[2];
    float*       out  = (float*)d_out;

    dim3 grid(TOKENS / 64);   // 256 blocks
    dim3 block(512);          // 8 waves: lane=token, wave=expert-group
    hipLaunchKernelGGL(topk_router_kernel, grid, block, 0, stream,
                       x, mask, gw, out);
}